// Round 1
// baseline (819.881 us; speedup 1.0000x reference)
//
#include <hip/hip_runtime.h>
#include <hip/hip_bf16.h>
#include <cfloat>

#define NROWS 4096
#define DDIM 1024
#define ICHUNKS 16
#define JTILES 32

// ---------------------------------------------------------------------------
// Kernel 1: per-row max (or 1.0 if normalize flag is 0). One wave per row.
// ---------------------------------------------------------------------------
__global__ __launch_bounds__(256) void rowmax_kernel(const float* __restrict__ feats,
                                                     const int* __restrict__ normflag,
                                                     float* __restrict__ rowmax) {
    const int wave = threadIdx.x >> 6;
    const int lane = threadIdx.x & 63;
    const int row  = blockIdx.x * 4 + wave;
    const float* fr = feats + (size_t)row * DDIM;
    float m = 0.0f;  // feats are uniform [0,1), nonnegative
    for (int d = lane * 4; d < DDIM; d += 256) {
        float4 v = *(const float4*)(fr + d);
        m = fmaxf(fmaxf(fmaxf(m, v.x), fmaxf(v.y, v.z)), v.w);
    }
    for (int off = 32; off > 0; off >>= 1) m = fmaxf(m, __shfl_xor(m, off));
    if (lane == 0) rowmax[row] = (*normflag != 0) ? m : 1.0f;
}

// ---------------------------------------------------------------------------
// Kernel 2: tiled Chebyshev distance + masked column-argmin partials.
// Block tile: 128 i-rows x 128 j-cols, d staged in chunks of 32 (fp32 LDS).
// Thread tile: 8x8 (rows ty+16k, cols tx+16jj). Grid: 32 j-tiles x 16 i-chunks.
// ---------------------------------------------------------------------------
__global__ __launch_bounds__(256, 2) void cheb_kernel(const float* __restrict__ feats,
                                                      const float* __restrict__ rowmax,
                                                      const int* __restrict__ labels,
                                                      float* __restrict__ pval,
                                                      int* __restrict__ pidx) {
    const int jt = blockIdx.x & (JTILES - 1);
    const int ic = blockIdx.x / JTILES;
    const int jBase = jt * 128;
    const int t  = threadIdx.x;
    const int ty = t & 15;
    const int tx = t >> 4;

    __shared__ __align__(16) float As[128 * 32];
    __shared__ __align__(16) float Bs[128 * 32];
    __shared__ int lblA[128];

    int lblB[8];
#pragma unroll
    for (int jj = 0; jj < 8; ++jj) lblB[jj] = labels[jBase + tx + 16 * jj];

    float run_val[8];
    int   run_idx[8];
#pragma unroll
    for (int jj = 0; jj < 8; ++jj) { run_val[jj] = FLT_MAX; run_idx[jj] = 0x7fffffff; }

    for (int it = 0; it < 2; ++it) {
        const int iBase = ic * 256 + it * 128;
        __syncthreads();                     // protect lblA reads of previous i-tile
        if (t < 128) lblA[t] = labels[iBase + t];

        float acc[8][8];
#pragma unroll
        for (int kk = 0; kk < 8; ++kk)
#pragma unroll
            for (int jj = 0; jj < 8; ++jj) acc[kk][jj] = 0.0f;

        for (int dc = 0; dc < DDIM / 32; ++dc) {
            const int dBase = dc * 32;
            __syncthreads();                 // LDS reuse from previous d-chunk
            // Stage A and B tiles (128 rows x 32 floats each), normalizing on the fly.
            // chunk swizzle: 16B chunk q of row r lands at chunk (q ^ (r&7)).
#pragma unroll
            for (int p = 0; p < 4; ++p) {
                const int c   = p * 256 + t;
                const int row = c >> 3;
                const int q   = c & 7;
                {
                    float4 v = *(const float4*)(feats + (size_t)(iBase + row) * DDIM + dBase + q * 4);
                    const float r = rowmax[iBase + row];
                    v.x /= r; v.y /= r; v.z /= r; v.w /= r;
                    *(float4*)(As + row * 32 + ((q ^ (row & 7)) << 2)) = v;
                }
                {
                    float4 v = *(const float4*)(feats + (size_t)(jBase + row) * DDIM + dBase + q * 4);
                    const float r = rowmax[jBase + row];
                    v.x /= r; v.y /= r; v.z /= r; v.w /= r;
                    *(float4*)(Bs + row * 32 + ((q ^ (row & 7)) << 2)) = v;
                }
            }
            __syncthreads();

#pragma unroll
            for (int q = 0; q < 8; ++q) {
                float4 a[8], b[8];
#pragma unroll
                for (int kk = 0; kk < 8; ++kk) {
                    const int r = ty + 16 * kk;
                    a[kk] = *(const float4*)(As + r * 32 + ((q ^ (r & 7)) << 2));
                }
#pragma unroll
                for (int jj = 0; jj < 8; ++jj) {
                    const int r = tx + 16 * jj;
                    b[jj] = *(const float4*)(Bs + r * 32 + ((q ^ (r & 7)) << 2));
                }
#pragma unroll
                for (int kk = 0; kk < 8; ++kk)
#pragma unroll
                    for (int jj = 0; jj < 8; ++jj) {
                        const float d0 = a[kk].x - b[jj].x;
                        const float d1 = a[kk].y - b[jj].y;
                        const float d2 = a[kk].z - b[jj].z;
                        const float d3 = a[kk].w - b[jj].w;
                        // shaped for v_max3_f32 fusion with |.| input modifiers
                        const float m0 = fmaxf(fmaxf(fabsf(d0), fabsf(d1)), fabsf(d2));
                        acc[kk][jj] = fmaxf(fmaxf(m0, fabsf(d3)), acc[kk][jj]);
                    }
            }
        }

        // Mask same-label rows, reduce over this i-tile.
#pragma unroll
        for (int jj = 0; jj < 8; ++jj) {
            float bv = FLT_MAX;
            int   bi = 0x7fffffff;
#pragma unroll
            for (int kk = 0; kk < 8; ++kk) {
                const int i = iBase + ty + 16 * kk;
                const float v = (lblA[ty + 16 * kk] == lblB[jj]) ? FLT_MAX : acc[kk][jj];
                if (v < bv || (v == bv && i < bi)) { bv = v; bi = i; }
            }
            // The 16 threads sharing this column are contiguous lanes of one wave.
#pragma unroll
            for (int off = 1; off < 16; off <<= 1) {
                const float ov = __shfl_xor(bv, off);
                const int   oi = __shfl_xor(bi, off);
                if (ov < bv || (ov == bv && oi < bi)) { bv = ov; bi = oi; }
            }
            if (bv < run_val[jj] || (bv == run_val[jj] && bi < run_idx[jj])) {
                run_val[jj] = bv; run_idx[jj] = bi;
            }
        }
    }

    if (ty == 0) {
#pragma unroll
        for (int jj = 0; jj < 8; ++jj) {
            const int j = jBase + tx + 16 * jj;
            pval[ic * NROWS + j] = run_val[jj];
            pidx[ic * NROWS + j] = run_idx[jj];
        }
    }
}

// ---------------------------------------------------------------------------
// Kernel 3: combine the 16 i-chunk partials per column, write outputs.
// out[0] = loss (mean of per-column min), out[1..4096] = image_idxs[closest].
// ---------------------------------------------------------------------------
__global__ __launch_bounds__(256) void finalize_kernel(const float* __restrict__ pval,
                                                       const int* __restrict__ pidx,
                                                       const int* __restrict__ image_idxs,
                                                       float* __restrict__ out) {
    const int t = threadIdx.x;
    float sum = 0.0f;
    for (int j = t; j < NROWS; j += 256) {
        float bv = pval[j];
        int   bi = pidx[j];
        for (int ic = 1; ic < ICHUNKS; ++ic) {
            const float v = pval[ic * NROWS + j];
            const int   i = pidx[ic * NROWS + j];
            if (v < bv || (v == bv && i < bi)) { bv = v; bi = i; }
        }
        out[1 + j] = (float)image_idxs[bi];
        sum += bv;
    }
    for (int off = 32; off > 0; off >>= 1) sum += __shfl_xor(sum, off);
    __shared__ float ssum[4];
    if ((t & 63) == 0) ssum[t >> 6] = sum;
    __syncthreads();
    if (t == 0) out[0] = (ssum[0] + ssum[1] + ssum[2] + ssum[3]) / (float)NROWS;
}

// ---------------------------------------------------------------------------
extern "C" void kernel_launch(void* const* d_in, const int* in_sizes, int n_in,
                              void* d_out, int out_size, void* d_ws, size_t ws_size,
                              hipStream_t stream) {
    const float* feats      = (const float*)d_in[0];
    const int*   labels     = (const int*)d_in[1];
    const int*   image_idxs = (const int*)d_in[2];
    const int*   normflag   = (const int*)d_in[3];
    float*       out        = (float*)d_out;

    float* rowmax = (float*)d_ws;                       // 4096 floats
    float* pval   = rowmax + NROWS;                     // 16*4096 floats
    int*   pidx   = (int*)(pval + ICHUNKS * NROWS);     // 16*4096 ints

    rowmax_kernel<<<NROWS / 4, 256, 0, stream>>>(feats, normflag, rowmax);
    cheb_kernel<<<JTILES * ICHUNKS, 256, 0, stream>>>(feats, rowmax, labels, pval, pidx);
    finalize_kernel<<<1, 256, 0, stream>>>(pval, pidx, image_idxs, out);
}

// Round 2
// 802.651 us; speedup vs baseline: 1.0215x; 1.0215x over previous
//
#include <hip/hip_runtime.h>
#include <hip/hip_bf16.h>
#include <cfloat>

#define NROWS 4096
#define DDIM 1024
#define ICHUNKS 32
#define JTILES 32

// acc = max(acc, |x|, |y|) in one VOP3 — compiler was not fusing this.
#define MAX3ABS(ACC, X, Y) \
    asm("v_max3_f32 %0, abs(%1), abs(%2), %0" : "+v"(ACC) : "v"(X), "v"(Y))

// ---------------------------------------------------------------------------
// Kernel 1a: per-row max + normalize into ws (fast path).
// One wave per row; row fits in 16 VGPR-float4s per lane round.
// ---------------------------------------------------------------------------
__global__ __launch_bounds__(256) void normalize_kernel(const float* __restrict__ feats,
                                                        const int* __restrict__ normflag,
                                                        float* __restrict__ normf) {
    const int wave = threadIdx.x >> 6;
    const int lane = threadIdx.x & 63;
    const int row  = blockIdx.x * 4 + wave;
    const float* fr = feats + (size_t)row * DDIM;
    float*       fw = normf + (size_t)row * DDIM;
    float4 v[4];
    float m = 0.0f;  // feats uniform [0,1): nonnegative
#pragma unroll
    for (int k = 0; k < 4; ++k) {
        v[k] = *(const float4*)(fr + lane * 4 + k * 256);
        m = fmaxf(fmaxf(fmaxf(m, v[k].x), fmaxf(v[k].y, v[k].z)), v[k].w);
    }
#pragma unroll
    for (int off = 32; off > 0; off >>= 1) m = fmaxf(m, __shfl_xor(m, off));
    const float r = (*normflag != 0) ? m : 1.0f;
#pragma unroll
    for (int k = 0; k < 4; ++k) {
        v[k].x /= r; v[k].y /= r; v[k].z /= r; v[k].w /= r;
        *(float4*)(fw + lane * 4 + k * 256) = v[k];
    }
}

// ---------------------------------------------------------------------------
// Kernel 1b (fallback when ws is small): per-row max only.
// ---------------------------------------------------------------------------
__global__ __launch_bounds__(256) void rowmax_kernel(const float* __restrict__ feats,
                                                     const int* __restrict__ normflag,
                                                     float* __restrict__ rowmax) {
    const int wave = threadIdx.x >> 6;
    const int lane = threadIdx.x & 63;
    const int row  = blockIdx.x * 4 + wave;
    const float* fr = feats + (size_t)row * DDIM;
    float m = 0.0f;
    for (int d = lane * 4; d < DDIM; d += 256) {
        float4 v = *(const float4*)(fr + d);
        m = fmaxf(fmaxf(fmaxf(m, v.x), fmaxf(v.y, v.z)), v.w);
    }
#pragma unroll
    for (int off = 32; off > 0; off >>= 1) m = fmaxf(m, __shfl_xor(m, off));
    if (lane == 0) rowmax[row] = (*normflag != 0) ? m : 1.0f;
}

// ---------------------------------------------------------------------------
// Kernel 2: tiled Chebyshev distance + masked column-argmin partials.
// Block tile 128i x 128j, d staged in chunks of 32 fp32 (16 KB x2 LDS).
// Thread tile 8x8 (rows ty+16kk, cols tx+16jj). Grid: 32 j-tiles x 32 i-chunks.
// NORM=true: divide by rowmax during staging (fallback). false: src pre-normalized.
// ---------------------------------------------------------------------------
template <bool NORM>
__global__ __launch_bounds__(256, 2) void cheb_kernel(const float* __restrict__ src,
                                                      const float* __restrict__ rowmax,
                                                      const int* __restrict__ labels,
                                                      float* __restrict__ pval,
                                                      int* __restrict__ pidx) {
    const int jt = blockIdx.x & (JTILES - 1);
    const int ic = blockIdx.x / JTILES;
    const int jBase = jt * 128;
    const int iBase = ic * 128;
    const int t  = threadIdx.x;
    const int ty = t & 15;
    const int tx = t >> 4;

    __shared__ __align__(16) float As[128 * 32];
    __shared__ __align__(16) float Bs[128 * 32];
    __shared__ int lblA[128];

    if (t < 128) lblA[t] = labels[iBase + t];

    int lblB[8];
#pragma unroll
    for (int jj = 0; jj < 8; ++jj) lblB[jj] = labels[jBase + tx + 16 * jj];

    float acc[8][8];
#pragma unroll
    for (int kk = 0; kk < 8; ++kk)
#pragma unroll
        for (int jj = 0; jj < 8; ++jj) acc[kk][jj] = 0.0f;

    // Hoisted swizzled-read bases: row r, chunk c -> byte r*128 + c*16,
    // c = q ^ (r&7). (ty&7) is shared by all 8 A-rows, (tx&7) by all 8 B-rows,
    // so per q only one xor+add per matrix; kk*2048 folds into ds offset imm.
    const int R4a = (ty & 7) << 4;
    const int R4b = (tx & 7) << 4;
    const char* Ab = (const char*)As + ty * 128;
    const char* Bb = (const char*)Bs + tx * 128;

    for (int dc = 0; dc < DDIM / 32; ++dc) {
        const int dBase = dc * 32;
        __syncthreads();                 // LDS reuse from previous d-chunk
#pragma unroll
        for (int p = 0; p < 4; ++p) {
            const int c   = p * 256 + t;
            const int row = c >> 3;
            const int q   = c & 7;
            {
                float4 v = *(const float4*)(src + (size_t)(iBase + row) * DDIM + dBase + q * 4);
                if (NORM) { const float r = rowmax[iBase + row]; v.x /= r; v.y /= r; v.z /= r; v.w /= r; }
                *(float4*)((char*)As + row * 128 + ((q ^ (row & 7)) << 4)) = v;
            }
            {
                float4 v = *(const float4*)(src + (size_t)(jBase + row) * DDIM + dBase + q * 4);
                if (NORM) { const float r = rowmax[jBase + row]; v.x /= r; v.y /= r; v.z /= r; v.w /= r; }
                *(float4*)((char*)Bs + row * 128 + ((q ^ (row & 7)) << 4)) = v;
            }
        }
        __syncthreads();

#pragma unroll
        for (int q = 0; q < 8; ++q) {
            const int oa = (q << 4) ^ R4a;
            const int ob = (q << 4) ^ R4b;
            float4 a[8], b[8];
#pragma unroll
            for (int kk = 0; kk < 8; ++kk) a[kk] = *(const float4*)(Ab + kk * 2048 + oa);
#pragma unroll
            for (int jj = 0; jj < 8; ++jj) b[jj] = *(const float4*)(Bb + jj * 2048 + ob);
#pragma unroll
            for (int kk = 0; kk < 8; ++kk)
#pragma unroll
                for (int jj = 0; jj < 8; ++jj) {
                    const float d0 = a[kk].x - b[jj].x;
                    const float d1 = a[kk].y - b[jj].y;
                    const float d2 = a[kk].z - b[jj].z;
                    const float d3 = a[kk].w - b[jj].w;
                    MAX3ABS(acc[kk][jj], d0, d1);
                    MAX3ABS(acc[kk][jj], d2, d3);
                }
        }
    }

    // Mask same-label rows, reduce over this 128-row i-chunk.
#pragma unroll
    for (int jj = 0; jj < 8; ++jj) {
        float bv = FLT_MAX;
        int   bi = 0x7fffffff;
#pragma unroll
        for (int kk = 0; kk < 8; ++kk) {
            const int i = iBase + ty + 16 * kk;
            const float v = (lblA[ty + 16 * kk] == lblB[jj]) ? FLT_MAX : acc[kk][jj];
            if (v < bv || (v == bv && i < bi)) { bv = v; bi = i; }
        }
        // The 16 threads sharing this column are contiguous lanes of one wave.
#pragma unroll
        for (int off = 1; off < 16; off <<= 1) {
            const float ov = __shfl_xor(bv, off);
            const int   oi = __shfl_xor(bi, off);
            if (ov < bv || (ov == bv && oi < bi)) { bv = ov; bi = oi; }
        }
        if (ty == 0) {
            const int j = jBase + tx + 16 * jj;
            pval[ic * NROWS + j] = bv;
            pidx[ic * NROWS + j] = bi;
        }
    }
}

// ---------------------------------------------------------------------------
// Kernel 3: combine the 32 i-chunk partials per column, write outputs.
// out[0] = loss (mean of per-column min), out[1..4096] = image_idxs[closest].
// ---------------------------------------------------------------------------
__global__ __launch_bounds__(256) void finalize_kernel(const float* __restrict__ pval,
                                                       const int* __restrict__ pidx,
                                                       const int* __restrict__ image_idxs,
                                                       float* __restrict__ out) {
    const int t = threadIdx.x;
    float sum = 0.0f;
    for (int j = t; j < NROWS; j += 256) {
        float bv = pval[j];
        int   bi = pidx[j];
        for (int ic = 1; ic < ICHUNKS; ++ic) {
            const float v = pval[ic * NROWS + j];
            const int   i = pidx[ic * NROWS + j];
            if (v < bv || (v == bv && i < bi)) { bv = v; bi = i; }
        }
        out[1 + j] = (float)image_idxs[bi];
        sum += bv;
    }
#pragma unroll
    for (int off = 32; off > 0; off >>= 1) sum += __shfl_xor(sum, off);
    __shared__ float ssum[4];
    if ((t & 63) == 0) ssum[t >> 6] = sum;
    __syncthreads();
    if (t == 0) out[0] = (ssum[0] + ssum[1] + ssum[2] + ssum[3]) / (float)NROWS;
}

// ---------------------------------------------------------------------------
extern "C" void kernel_launch(void* const* d_in, const int* in_sizes, int n_in,
                              void* d_out, int out_size, void* d_ws, size_t ws_size,
                              hipStream_t stream) {
    const float* feats      = (const float*)d_in[0];
    const int*   labels     = (const int*)d_in[1];
    const int*   image_idxs = (const int*)d_in[2];
    const int*   normflag   = (const int*)d_in[3];
    float*       out        = (float*)d_out;

    const size_t normBytes = (size_t)NROWS * DDIM * sizeof(float);     // 16 MB
    const size_t partBytes = (size_t)ICHUNKS * NROWS * 8;              // 1 MB

    if (ws_size >= normBytes + partBytes) {
        float* normf = (float*)d_ws;
        float* pval  = (float*)((char*)d_ws + normBytes);
        int*   pidx  = (int*)(pval + ICHUNKS * NROWS);
        normalize_kernel<<<NROWS / 4, 256, 0, stream>>>(feats, normflag, normf);
        cheb_kernel<false><<<JTILES * ICHUNKS, 256, 0, stream>>>(normf, nullptr, labels, pval, pidx);
        finalize_kernel<<<1, 256, 0, stream>>>(pval, pidx, image_idxs, out);
    } else {
        float* rowmax = (float*)d_ws;
        float* pval   = rowmax + NROWS;
        int*   pidx   = (int*)(pval + ICHUNKS * NROWS);
        rowmax_kernel<<<NROWS / 4, 256, 0, stream>>>(feats, normflag, rowmax);
        cheb_kernel<true><<<JTILES * ICHUNKS, 256, 0, stream>>>(feats, rowmax, labels, pval, pidx);
        finalize_kernel<<<1, 256, 0, stream>>>(pval, pidx, image_idxs, out);
    }
}

// Round 3
// 328.893 us; speedup vs baseline: 2.4928x; 2.4405x over previous
//
#include <hip/hip_runtime.h>
#include <hip/hip_bf16.h>
#include <cfloat>

#define NROWS 4096
#define DDIM 1024
#define NT 64                    // 64x64 tiles per dimension
#define NBLK (NT * (NT + 1) / 2) // 2080 triangular blocks
#define NSLOT (NT + 1)           // 65 partial slots per column

// acc = max(acc, |x|, |y|) in one VOP3.
#define MAX3ABS(ACC, X, Y) \
    asm("v_max3_f32 %0, abs(%1), abs(%2), %0" : "+v"(ACC) : "v"(X), "v"(Y))

// lexicographic (val, idx) merge: keep smaller val, tie -> smaller idx
#define MERGE(BV, BI, V, I) \
    do { if ((V) < (BV) || ((V) == (BV) && (I) < (BI))) { BV = (V); BI = (I); } } while (0)

// ---------------------------------------------------------------------------
// Kernel 1a: per-row max + normalize into ws (fast path). One wave per row.
// ---------------------------------------------------------------------------
__global__ __launch_bounds__(256) void normalize_kernel(const float* __restrict__ feats,
                                                        const int* __restrict__ normflag,
                                                        float* __restrict__ normf) {
    const int wave = threadIdx.x >> 6;
    const int lane = threadIdx.x & 63;
    const int row  = blockIdx.x * 4 + wave;
    const float* fr = feats + (size_t)row * DDIM;
    float*       fw = normf + (size_t)row * DDIM;
    float4 v[4];
    float m = 0.0f;  // feats uniform [0,1): nonnegative
#pragma unroll
    for (int k = 0; k < 4; ++k) {
        v[k] = *(const float4*)(fr + lane * 4 + k * 256);
        m = fmaxf(fmaxf(fmaxf(m, v[k].x), fmaxf(v[k].y, v[k].z)), v[k].w);
    }
#pragma unroll
    for (int off = 32; off > 0; off >>= 1) m = fmaxf(m, __shfl_xor(m, off));
    const float r = (*normflag != 0) ? m : 1.0f;
#pragma unroll
    for (int k = 0; k < 4; ++k) {
        v[k].x /= r; v[k].y /= r; v[k].z /= r; v[k].w /= r;
        *(float4*)(fw + lane * 4 + k * 256) = v[k];
    }
}

// Kernel 1b (fallback when ws is small): per-row max only.
__global__ __launch_bounds__(256) void rowmax_kernel(const float* __restrict__ feats,
                                                     const int* __restrict__ normflag,
                                                     float* __restrict__ rowmax) {
    const int wave = threadIdx.x >> 6;
    const int lane = threadIdx.x & 63;
    const int row  = blockIdx.x * 4 + wave;
    const float* fr = feats + (size_t)row * DDIM;
    float m = 0.0f;
    for (int d = lane * 4; d < DDIM; d += 256) {
        float4 v = *(const float4*)(fr + d);
        m = fmaxf(fmaxf(fmaxf(m, v.x), fmaxf(v.y, v.z)), v.w);
    }
#pragma unroll
    for (int off = 32; off > 0; off >>= 1) m = fmaxf(m, __shfl_xor(m, off));
    if (lane == 0) rowmax[row] = (*normflag != 0) ? m : 1.0f;
}

// ---------------------------------------------------------------------------
// Kernel 2: triangular 64x64 tile blocks. Each block computes the Chebyshev
// distances for its (ta, tb) tile pair (ta <= tb) once, and emits argmin
// partials in BOTH orientations (symmetry): slot ta for columns of tb-tile,
// slot tb+1 for columns of ta-tile. Waves = 2x2 quadrants (32x32), threads
// 8x8 per wave, 4x4 per thread. LDS linear 128B stride, xor swizzle q^(row&7):
// A-reads have 8 distinct rows (row&7 = ty8) per 16-lane group -> conflict-free.
// ---------------------------------------------------------------------------
template <bool NORM>
__global__ __launch_bounds__(256, 5) void cheb_kernel(const float* __restrict__ src,
                                                      const float* __restrict__ rowmax,
                                                      const int* __restrict__ labels,
                                                      float* __restrict__ pval,
                                                      int* __restrict__ pidx) {
    // XCD-bijective swizzle (NBLK % 8 == 0), then triangular decode.
    int bid = blockIdx.x;
    bid = (bid & 7) * (NBLK / 8) + (bid >> 3);
    float fs = sqrtf((float)((2 * NT + 1) * (2 * NT + 1) - 8 * bid));
    int ta = (int)(((float)(2 * NT + 1) - fs) * 0.5f);
    while ((ta + 1) * NT - ((ta + 1) * ta) / 2 <= bid) ++ta;      // start(ta+1) <= bid
    while (ta * NT - (ta * (ta - 1)) / 2 > bid) --ta;             // start(ta)  >  bid
    const int tb = ta + (bid - (ta * NT - (ta * (ta - 1)) / 2));
    const int iBase = ta * 64;
    const int jBase = tb * 64;

    const int t   = threadIdx.x;
    const int w   = t >> 6;          // wave 0..3
    const int rH  = (w & 1) * 32;    // row half of tile
    const int cH  = (w >> 1) * 32;   // col half of tile
    const int ty8 = t & 7;
    const int tx8 = (t >> 3) & 7;

    __shared__ __align__(16) float As[64 * 32];
    __shared__ __align__(16) float Bs[64 * 32];
    __shared__ float sval[4 * 32];
    __shared__ int   sidx[4 * 32];

    int lA[4], lB[4];
#pragma unroll
    for (int kk = 0; kk < 4; ++kk) lA[kk] = labels[iBase + rH + ty8 + 8 * kk];
#pragma unroll
    for (int jj = 0; jj < 4; ++jj) lB[jj] = labels[jBase + cH + tx8 + 8 * jj];

    float acc[4][4];
#pragma unroll
    for (int kk = 0; kk < 4; ++kk)
#pragma unroll
        for (int jj = 0; jj < 4; ++jj) acc[kk][jj] = 0.0f;

    // Staging assignment: element e = p*256+t -> row = e>>3 (0..63), q = e&7.
    const int r0  = t >> 3;                 // rows r0 (p=0) and r0+32 (p=1)
    const int q0  = t & 7;
    const int lo0 = r0 * 32 + 4 * (q0 ^ (r0 & 7));
    const int lo1 = (r0 + 32) * 32 + 4 * (q0 ^ ((r0 + 32) & 7));
    const float* gA0 = src + (size_t)(iBase + r0) * DDIM + 4 * q0;
    const float* gA1 = src + (size_t)(iBase + r0 + 32) * DDIM + 4 * q0;
    const float* gB0 = src + (size_t)(jBase + r0) * DDIM + 4 * q0;
    const float* gB1 = src + (size_t)(jBase + r0 + 32) * DDIM + 4 * q0;
    float rA0 = 1.0f, rA1 = 1.0f, rB0 = 1.0f, rB1 = 1.0f;
    if (NORM) {
        rA0 = rowmax[iBase + r0]; rA1 = rowmax[iBase + r0 + 32];
        rB0 = rowmax[jBase + r0]; rB1 = rowmax[jBase + r0 + 32];
    }

    for (int dc = 0; dc < DDIM / 32; ++dc) {
        const int dB = dc * 32;
        __syncthreads();
        {
            float4 va0 = *(const float4*)(gA0 + dB);
            float4 va1 = *(const float4*)(gA1 + dB);
            float4 vb0 = *(const float4*)(gB0 + dB);
            float4 vb1 = *(const float4*)(gB1 + dB);
            if (NORM) {
                va0.x /= rA0; va0.y /= rA0; va0.z /= rA0; va0.w /= rA0;
                va1.x /= rA1; va1.y /= rA1; va1.z /= rA1; va1.w /= rA1;
                vb0.x /= rB0; vb0.y /= rB0; vb0.z /= rB0; vb0.w /= rB0;
                vb1.x /= rB1; vb1.y /= rB1; vb1.z /= rB1; vb1.w /= rB1;
            }
            *(float4*)(As + lo0) = va0;
            *(float4*)(As + lo1) = va1;
            *(float4*)(Bs + lo0) = vb0;
            *(float4*)(Bs + lo1) = vb1;
        }
        __syncthreads();

#pragma unroll
        for (int q = 0; q < 8; ++q) {
            float4 a[4], b[4];
#pragma unroll
            for (int kk = 0; kk < 4; ++kk)
                a[kk] = *(const float4*)(As + (rH + ty8 + 8 * kk) * 32 + 4 * (q ^ ty8));
#pragma unroll
            for (int jj = 0; jj < 4; ++jj)
                b[jj] = *(const float4*)(Bs + (cH + tx8 + 8 * jj) * 32 + 4 * (q ^ tx8));
#pragma unroll
            for (int kk = 0; kk < 4; ++kk)
#pragma unroll
                for (int jj = 0; jj < 4; ++jj) {
                    const float d0 = a[kk].x - b[jj].x;
                    const float d1 = a[kk].y - b[jj].y;
                    const float d2 = a[kk].z - b[jj].z;
                    const float d3 = a[kk].w - b[jj].w;
                    MAX3ABS(acc[kk][jj], d0, d1);
                    MAX3ABS(acc[kk][jj], d2, d3);
                }
        }
    }

    // ---- Orientation 1: per column (of tb-tile), min over this block's rows.
    {
        float bv1[4]; int bi1[4];
#pragma unroll
        for (int jj = 0; jj < 4; ++jj) {
            float bv = FLT_MAX; int bi = 0x7fffffff;
#pragma unroll
            for (int kk = 0; kk < 4; ++kk) {
                const int i = iBase + rH + ty8 + 8 * kk;
                const float v = (lA[kk] == lB[jj]) ? FLT_MAX : acc[kk][jj];
                MERGE(bv, bi, v, i);
            }
#pragma unroll
            for (int off = 1; off <= 4; off <<= 1) {     // reduce over ty8
                const float ov = __shfl_xor(bv, off);
                const int   oi = __shfl_xor(bi, off);
                MERGE(bv, bi, ov, oi);
            }
            bv1[jj] = bv; bi1[jj] = bi;
        }
        if (ty8 == 0) {
#pragma unroll
            for (int jj = 0; jj < 4; ++jj) {
                const int cq = tx8 + 8 * jj;             // col within quadrant
                sval[w * 32 + cq] = bv1[jj];
                sidx[w * 32 + cq] = bi1[jj];
            }
        }
    }
    __syncthreads();
    if (t < 64) {        // combine the two row-half waves per column
        const int C = t, ch = C >> 5, cq = C & 31;
        const int w1 = ch * 2, w2 = ch * 2 + 1;
        float bv = sval[w1 * 32 + cq]; int bi = sidx[w1 * 32 + cq];
        MERGE(bv, bi, sval[w2 * 32 + cq], sidx[w2 * 32 + cq]);
        pval[ta * NROWS + jBase + C] = bv;
        pidx[ta * NROWS + jBase + C] = bi;
    }
    __syncthreads();

    // ---- Orientation 2: per row (of ta-tile), min over this block's cols.
#pragma unroll
    for (int kk = 0; kk < 4; ++kk) {
        float bv = FLT_MAX; int bi = 0x7fffffff;
#pragma unroll
        for (int jj = 0; jj < 4; ++jj) {
            const int j = jBase + cH + tx8 + 8 * jj;
            const float v = (lA[kk] == lB[jj]) ? FLT_MAX : acc[kk][jj];
            MERGE(bv, bi, v, j);
        }
#pragma unroll
        for (int off = 8; off <= 32; off <<= 1) {        // reduce over tx8
            const float ov = __shfl_xor(bv, off);
            const int   oi = __shfl_xor(bi, off);
            MERGE(bv, bi, ov, oi);
        }
        if (((t >> 3) & 7) == 0) {
            const int rq = ty8 + 8 * kk;                 // row within quadrant
            sval[w * 32 + rq] = bv;
            sidx[w * 32 + rq] = bi;
        }
    }
    __syncthreads();
    if (t < 64) {        // combine the two col-half waves per row
        const int R = t, rh = R >> 5, rq = R & 31;
        const int w1 = rh, w2 = rh + 2;
        float bv = sval[w1 * 32 + rq]; int bi = sidx[w1 * 32 + rq];
        MERGE(bv, bi, sval[w2 * 32 + rq], sidx[w2 * 32 + rq]);
        pval[(tb + 1) * NROWS + iBase + R] = bv;
        pidx[(tb + 1) * NROWS + iBase + R] = bi;
    }
}

// ---------------------------------------------------------------------------
// Kernel 3a: combine 65 partial slots per column; write indices + colmin.
// ---------------------------------------------------------------------------
__global__ __launch_bounds__(256) void finalizeA_kernel(const float* __restrict__ pval,
                                                        const int* __restrict__ pidx,
                                                        const int* __restrict__ image_idxs,
                                                        float* __restrict__ out,
                                                        float* __restrict__ colmin) {
    const int j = blockIdx.x * 256 + threadIdx.x;
    float bv = FLT_MAX; int bi = 0x7fffffff;
    for (int s = 0; s < NSLOT; ++s) {
        const float v = pval[s * NROWS + j];
        const int   i = pidx[s * NROWS + j];
        MERGE(bv, bi, v, i);
    }
    out[1 + j] = (float)image_idxs[bi];
    colmin[j] = bv;
}

// Kernel 3b: deterministic sum of colmin -> loss.
__global__ __launch_bounds__(256) void finalizeB_kernel(const float* __restrict__ colmin,
                                                        float* __restrict__ out) {
    const int t = threadIdx.x;
    float s = 0.0f;
#pragma unroll
    for (int k = 0; k < 16; ++k) s += colmin[t + 256 * k];
#pragma unroll
    for (int off = 32; off > 0; off >>= 1) s += __shfl_xor(s, off);
    __shared__ float ss[4];
    if ((t & 63) == 0) ss[t >> 6] = s;
    __syncthreads();
    if (t == 0) out[0] = (ss[0] + ss[1] + ss[2] + ss[3]) / (float)NROWS;
}

// ---------------------------------------------------------------------------
extern "C" void kernel_launch(void* const* d_in, const int* in_sizes, int n_in,
                              void* d_out, int out_size, void* d_ws, size_t ws_size,
                              hipStream_t stream) {
    const float* feats      = (const float*)d_in[0];
    const int*   labels     = (const int*)d_in[1];
    const int*   image_idxs = (const int*)d_in[2];
    const int*   normflag   = (const int*)d_in[3];
    float*       out        = (float*)d_out;

    const size_t normBytes = (size_t)NROWS * DDIM * sizeof(float);          // 16 MB
    const size_t partBytes = (size_t)NSLOT * NROWS * 8 + NROWS * 4;         // ~2.15 MB

    if (ws_size >= normBytes + partBytes) {
        float* normf  = (float*)d_ws;
        float* pval   = (float*)((char*)d_ws + normBytes);
        int*   pidx   = (int*)(pval + NSLOT * NROWS);
        float* colmin = (float*)(pidx + NSLOT * NROWS);
        normalize_kernel<<<NROWS / 4, 256, 0, stream>>>(feats, normflag, normf);
        cheb_kernel<false><<<NBLK, 256, 0, stream>>>(normf, nullptr, labels, pval, pidx);
        finalizeA_kernel<<<NROWS / 256, 256, 0, stream>>>(pval, pidx, image_idxs, out, colmin);
        finalizeB_kernel<<<1, 256, 0, stream>>>(colmin, out);
    } else {
        float* rowmax = (float*)d_ws;
        float* pval   = rowmax + NROWS;
        int*   pidx   = (int*)(pval + NSLOT * NROWS);
        float* colmin = (float*)(pidx + NSLOT * NROWS);
        rowmax_kernel<<<NROWS / 4, 256, 0, stream>>>(feats, normflag, rowmax);
        cheb_kernel<true><<<NBLK, 256, 0, stream>>>(feats, rowmax, labels, pval, pidx);
        finalizeA_kernel<<<NROWS / 256, 256, 0, stream>>>(pval, pidx, image_idxs, out, colmin);
        finalizeB_kernel<<<1, 256, 0, stream>>>(colmin, out);
    }
}